// Round 11
// baseline (65.398 us; speedup 1.0000x reference)
//
#include <hip/hip_runtime.h>

#define NB 16
#define IN_CH 64
#define OUT_CH 256
#define NH 48
#define NW 48
#define NPIX (NH * NW)                 // 2304
#define ROW_STRIDE 52                  // dwords per staged halo row
#define CH_STRIDE (4 * ROW_STRIDE)     // 208 dwords per channel (4 halo rows)
#define LDS_DW (IN_CH * CH_STRIDE)     // 13312 dwords = 53,248 B -> 3 blocks/CU
#define NITEMS (IN_CH * 4 * 26)        // 6656 float2 staging items
#define META_F4 9                      // per o: [0..1]=8 int offsets, [2..8]=7 node weights

__constant__ float c_gate[16 * 4] = {
    0.f, 0.f, 0.f, 0.f,
    0.f, 0.f, 0.f, 1.f,
    0.f, 1.f, 0.f, -1.f,
    0.f, 1.f, 0.f, 0.f,
    0.f, 0.f, 1.f, -1.f,
    0.f, 0.f, 1.f, 0.f,
    0.f, 1.f, 1.f, -2.f,
    0.f, 1.f, 1.f, -1.f,
    1.f, -1.f, -1.f, 1.f,
    1.f, -1.f, -1.f, 2.f,
    1.f, 0.f, -1.f, 0.f,
    1.f, 0.f, -1.f, 1.f,
    1.f, -1.f, 0.f, 0.f,
    1.f, -1.f, 0.f, 1.f,
    1.f, 0.f, 0.f, -1.f,
    1.f, 0.f, 0.f, 0.f
};

// meta[o][36 dw]: 0..7 = int LDS dword offsets (c*CH_STRIDE + di*ROW_STRIDE + dj),
//                8..35 = 7 nodes x 4 floats (softmax(logits) @ GATE_COEFF)
__global__ __launch_bounds__(256) void prep_kernel(
    const float* __restrict__ logits,
    const int*   __restrict__ leaf_idx,
    float*       __restrict__ meta)
{
    int t = blockIdx.x * 256 + threadIdx.x;
    if (t < OUT_CH * 8) {
        int idx = leaf_idx[t];
        int c  = idx / 9;
        int k  = idx - c * 9;
        int di = k / 3;
        int dj = k - di * 3;
        reinterpret_cast<int*>(meta)[(t >> 3) * 36 + (t & 7)] =
            c * CH_STRIDE + di * ROW_STRIDE + dj;
    } else {
        int t2 = t - OUT_CH * 8;
        if (t2 >= OUT_CH * 7) return;
        int o = t2 / 7;
        int n = t2 - o * 7;
        const float* lg = logits + (size_t)t2 * 16;

        float m = lg[0];
#pragma unroll
        for (int g = 1; g < 16; ++g) m = fmaxf(m, lg[g]);
        float e16[16];
        float s = 0.f;
#pragma unroll
        for (int g = 0; g < 16; ++g) { e16[g] = expf(lg[g] - m); s += e16[g]; }
        float inv = 1.f / s;

        float w0 = 0.f, w1 = 0.f, w2 = 0.f, w3 = 0.f;
#pragma unroll
        for (int g = 0; g < 16; ++g) {
            float p = e16[g] * inv;
            w0 += p * c_gate[g * 4 + 0];
            w1 += p * c_gate[g * 4 + 1];
            w2 += p * c_gate[g * 4 + 2];
            w3 += p * c_gate[g * 4 + 3];
        }
        float* mw = meta + o * 36 + 8 + n * 4;
        mw[0] = w0; mw[1] = w1; mw[2] = w2; mw[3] = w3;
    }
}

// grid = (24 bands, 2 o-halves, 16 batches), block = 512 (8 waves), 3 blocks/CU.
// Wave = 2 o-groups x 32 px lanes. Lane pxg covers linear pixels
// {pxg, pxg+32, pxg+64} of the 2-row band.
// Halo row mapping: image row gr lives at halo row gr-r0+1, so output row r0's
// gather rows (r0-1+di) are at halo rows di -> px0 base = off_j + pxg + 1.
// Deltas from px0's address (lane-uniform where it matters):
//   px2 = +68 dwords (row +1, col +16; uniform) -> ds_read2_b32 offsets {0,68}
//   px1 = +32 (pxg<16: same row, col+32) or +36 (pxg>=16: row+1, col-16)
// DS instructions per channel-iter: 16 (was 24). Stores identical to R6
// (32-lane contiguous dword groups at +0,+32,+64 -> clean 128B lines).
__global__ __launch_bounds__(512, 6) void ltc_kernel(
    const float*  __restrict__ x,     // [B][64][48][48]
    const float4* __restrict__ meta,  // [OUT_CH][9]
    float*        __restrict__ out)   // [B][OUT_CH][48][48]
{
    __shared__ float lds[LDS_DW];

    const int band  = blockIdx.x;     // 0..23
    const int ohalf = blockIdx.y;     // 0..1
    const int b     = blockIdx.z;     // 0..15
    const int r0    = band * 2;
    const int tid   = threadIdx.x;

    // ---- stage 4-row halo as float2: layout [c][4][52], image col g at lds col g+2 ----
    const float* xb = x + (size_t)b * IN_CH * NPIX;
    for (int it = tid; it < NITEMS; it += 512) {
        int c   = it / 104;                 // 104 = 4 rows * 26 pairs
        int rem = it - c * 104;
        int r4  = rem / 26;
        int p   = rem - r4 * 26;            // pair: lds cols 2p, 2p+1
        int gr  = r0 - 1 + r4;
        float2 v = make_float2(0.f, 0.f);
        if (p > 0 && p < 25 && (unsigned)gr < NH)
            v = *reinterpret_cast<const float2*>(xb + (c * NH + gr) * NW + (2 * p - 2));
        *reinterpret_cast<float2*>(&lds[c * CH_STRIDE + r4 * ROW_STRIDE + 2 * p]) = v;
    }
    __syncthreads();

    const int lane = tid & 63;
    const int wid  = tid >> 6;               // 0..7
    const int og   = lane >> 5;              // 0..1
    const int pxg  = lane & 31;              // 0..31
    const int o0   = ohalf * 128 + ((wid << 1) | og) * 8;  // first of 8 channels

    const int cbase = pxg + 1;               // px0 base col offset (halo row di)
    const int d1    = (pxg < 16) ? 32 : 36;  // px1 delta (dwords)

    const float4* mptr  = meta + (size_t)o0 * META_F4;
    float*        pbase = out + ((size_t)b * OUT_CH + o0) * NPIX + r0 * NW + pxg;

#pragma unroll 1
    for (int i = 0; i < 8; ++i) {
        float4 M0 = mptr[0], M1 = mptr[1];
        float4 W0 = mptr[2], W1 = mptr[3], W2 = mptr[4];
        float4 W3 = mptr[5], W4 = mptr[6], W5 = mptr[7], W6 = mptr[8];

        int vb[8];
        vb[0] = __float_as_int(M0.x) + cbase;
        vb[1] = __float_as_int(M0.y) + cbase;
        vb[2] = __float_as_int(M0.z) + cbase;
        vb[3] = __float_as_int(M0.w) + cbase;
        vb[4] = __float_as_int(M1.x) + cbase;
        vb[5] = __float_as_int(M1.y) + cbase;
        vb[6] = __float_as_int(M1.z) + cbase;
        vb[7] = __float_as_int(M1.w) + cbase;

        float v0[8], v1[8], v2[8];
#pragma unroll
        for (int j = 0; j < 8; ++j) {
            const int a = vb[j];
            v0[j] = lds[a];          // px0   -> ds_read2_b32 {0,68} with v2
            v2[j] = lds[a + 68];     // px2
            v1[j] = lds[a + d1];     // px1   -> ds_read_b32
        }

        {   // tree for px0
            float t0 = fmaf(v0[1], fmaf(W0.w, v0[0], W0.z), fmaf(W0.y, v0[0], W0.x));
            float t1 = fmaf(v0[3], fmaf(W1.w, v0[2], W1.z), fmaf(W1.y, v0[2], W1.x));
            float t2 = fmaf(v0[5], fmaf(W2.w, v0[4], W2.z), fmaf(W2.y, v0[4], W2.x));
            float t3 = fmaf(v0[7], fmaf(W3.w, v0[6], W3.z), fmaf(W3.y, v0[6], W3.x));
            float u0 = fmaf(t1, fmaf(W4.w, t0, W4.z), fmaf(W4.y, t0, W4.x));
            float u1 = fmaf(t3, fmaf(W5.w, t2, W5.z), fmaf(W5.y, t2, W5.x));
            pbase[0] = fmaf(u1, fmaf(W6.w, u0, W6.z), fmaf(W6.y, u0, W6.x));
        }
        {   // tree for px1
            float t0 = fmaf(v1[1], fmaf(W0.w, v1[0], W0.z), fmaf(W0.y, v1[0], W0.x));
            float t1 = fmaf(v1[3], fmaf(W1.w, v1[2], W1.z), fmaf(W1.y, v1[2], W1.x));
            float t2 = fmaf(v1[5], fmaf(W2.w, v1[4], W2.z), fmaf(W2.y, v1[4], W2.x));
            float t3 = fmaf(v1[7], fmaf(W3.w, v1[6], W3.z), fmaf(W3.y, v1[6], W3.x));
            float u0 = fmaf(t1, fmaf(W4.w, t0, W4.z), fmaf(W4.y, t0, W4.x));
            float u1 = fmaf(t3, fmaf(W5.w, t2, W5.z), fmaf(W5.y, t2, W5.x));
            pbase[32] = fmaf(u1, fmaf(W6.w, u0, W6.z), fmaf(W6.y, u0, W6.x));
        }
        {   // tree for px2
            float t0 = fmaf(v2[1], fmaf(W0.w, v2[0], W0.z), fmaf(W0.y, v2[0], W0.x));
            float t1 = fmaf(v2[3], fmaf(W1.w, v2[2], W1.z), fmaf(W1.y, v2[2], W1.x));
            float t2 = fmaf(v2[5], fmaf(W2.w, v2[4], W2.z), fmaf(W2.y, v2[4], W2.x));
            float t3 = fmaf(v2[7], fmaf(W3.w, v2[6], W3.z), fmaf(W3.y, v2[6], W3.x));
            float u0 = fmaf(t1, fmaf(W4.w, t0, W4.z), fmaf(W4.y, t0, W4.x));
            float u1 = fmaf(t3, fmaf(W5.w, t2, W5.z), fmaf(W5.y, t2, W5.x));
            pbase[64] = fmaf(u1, fmaf(W6.w, u0, W6.z), fmaf(W6.y, u0, W6.x));
        }

        mptr  += META_F4;
        pbase += NPIX;
    }
}

extern "C" void kernel_launch(void* const* d_in, const int* in_sizes, int n_in,
                              void* d_out, int out_size, void* d_ws, size_t ws_size,
                              hipStream_t stream) {
    const float* x        = (const float*)d_in[0];
    const float* logits   = (const float*)d_in[1];
    const int*   leaf_idx = (const int*)d_in[2];
    float*       out      = (float*)d_out;
    float*       meta     = (float*)d_ws;    // 256*36 dwords = 36,864 B

    prep_kernel<<<15, 256, 0, stream>>>(logits, leaf_idx, meta);

    dim3 grid(24, 2, NB);
    ltc_kernel<<<grid, 512, 0, stream>>>(x, (const float4*)meta, out);
}

// Round 12
// 33.851 us; speedup vs baseline: 1.9319x; 1.9319x over previous
//
#include <hip/hip_runtime.h>

#define NB 16
#define IN_CH 64
#define OUT_CH 256
#define NH 48
#define NW 48
#define NPIX (NH * NW)                 // 2304
#define ROW_STRIDE 52                  // dwords per staged halo row
#define CH_STRIDE (4 * ROW_STRIDE)     // 208 dwords per channel (4 halo rows)
#define LDS_DW (IN_CH * CH_STRIDE)     // 13312 dwords = 53,248 B -> 3 blocks/CU
#define NITEMS (IN_CH * 4 * 26)        // 6656 float2 staging items
#define META_F4 9                      // per o: [0..1]=8 int offsets, [2..8]=7 node weights

__constant__ float c_gate[16 * 4] = {
    0.f, 0.f, 0.f, 0.f,
    0.f, 0.f, 0.f, 1.f,
    0.f, 1.f, 0.f, -1.f,
    0.f, 1.f, 0.f, 0.f,
    0.f, 0.f, 1.f, -1.f,
    0.f, 0.f, 1.f, 0.f,
    0.f, 1.f, 1.f, -2.f,
    0.f, 1.f, 1.f, -1.f,
    1.f, -1.f, -1.f, 1.f,
    1.f, -1.f, -1.f, 2.f,
    1.f, 0.f, -1.f, 0.f,
    1.f, 0.f, -1.f, 1.f,
    1.f, -1.f, 0.f, 0.f,
    1.f, -1.f, 0.f, 1.f,
    1.f, 0.f, 0.f, -1.f,
    1.f, 0.f, 0.f, 0.f
};

// meta[o][36 dw]: 0..7 = int LDS dword offsets (c*CH_STRIDE + di*ROW_STRIDE + dj),
//                8..35 = 7 nodes x 4 floats (softmax(logits) @ GATE_COEFF)
__global__ __launch_bounds__(256) void prep_kernel(
    const float* __restrict__ logits,
    const int*   __restrict__ leaf_idx,
    float*       __restrict__ meta)
{
    int t = blockIdx.x * 256 + threadIdx.x;
    if (t < OUT_CH * 8) {
        int idx = leaf_idx[t];
        int c  = idx / 9;
        int k  = idx - c * 9;
        int di = k / 3;
        int dj = k - di * 3;
        reinterpret_cast<int*>(meta)[(t >> 3) * 36 + (t & 7)] =
            c * CH_STRIDE + di * ROW_STRIDE + dj;
    } else {
        int t2 = t - OUT_CH * 8;
        if (t2 >= OUT_CH * 7) return;
        int o = t2 / 7;
        int n = t2 - o * 7;
        const float* lg = logits + (size_t)t2 * 16;

        float m = lg[0];
#pragma unroll
        for (int g = 1; g < 16; ++g) m = fmaxf(m, lg[g]);
        float e16[16];
        float s = 0.f;
#pragma unroll
        for (int g = 0; g < 16; ++g) { e16[g] = expf(lg[g] - m); s += e16[g]; }
        float inv = 1.f / s;

        float w0 = 0.f, w1 = 0.f, w2 = 0.f, w3 = 0.f;
#pragma unroll
        for (int g = 0; g < 16; ++g) {
            float p = e16[g] * inv;
            w0 += p * c_gate[g * 4 + 0];
            w1 += p * c_gate[g * 4 + 1];
            w2 += p * c_gate[g * 4 + 2];
            w3 += p * c_gate[g * 4 + 3];
        }
        float* mw = meta + o * 36 + 8 + n * 4;
        mw[0] = w0; mw[1] = w1; mw[2] = w2; mw[3] = w3;
    }
}

// grid = (24 bands, 2 o-halves, 16 batches), block = 512 (8 waves).
// __launch_bounds__(512, 3): 3 blocks/CU (the LDS limit) -> VGPR cap 85.
// R11's (512,6) was treated as 6 BLOCKS/CU -> 12 waves/SIMD -> VGPR capped
// at 40 -> scratch spills (WRITE_SIZE 165MB, FETCH 42MB). This fixes that.
// Wave = 2 o-groups x 32 px lanes (stores 32-lane contiguous = full 128B).
__global__ __launch_bounds__(512, 3) void ltc_kernel(
    const float*  __restrict__ x,     // [B][64][48][48]
    const float4* __restrict__ meta,  // [OUT_CH][9] (+1 record pad readable)
    float*        __restrict__ out)   // [B][OUT_CH][48][48]
{
    __shared__ float lds[LDS_DW];

    const int band  = blockIdx.x;     // 0..23
    const int ohalf = blockIdx.y;     // 0..1
    const int b     = blockIdx.z;     // 0..15
    const int r0    = band * 2;
    const int tid   = threadIdx.x;

    // ---- stage 4-row halo as float2: layout [c][4][52], image col g at lds col g+2 ----
    const float* xb = x + (size_t)b * IN_CH * NPIX;
    for (int it = tid; it < NITEMS; it += 512) {
        int c   = it / 104;                 // 104 = 4 rows * 26 pairs
        int rem = it - c * 104;
        int r4  = rem / 26;
        int p   = rem - r4 * 26;            // pair: lds cols 2p, 2p+1
        int gr  = r0 - 1 + r4;
        float2 v = make_float2(0.f, 0.f);
        if (p > 0 && p < 25 && (unsigned)gr < NH)
            v = *reinterpret_cast<const float2*>(xb + (c * NH + gr) * NW + (2 * p - 2));
        *reinterpret_cast<float2*>(&lds[c * CH_STRIDE + r4 * ROW_STRIDE + 2 * p]) = v;
    }
    __syncthreads();

    const int lane = tid & 63;
    const int wid  = tid >> 6;               // 0..7
    const int og   = lane >> 5;              // 0..1
    const int pxg  = lane & 31;              // 0..31
    const int o0   = ohalf * 128 + ((wid << 1) | og) * 8;  // first of 8 channels

    // per-lane pixel bases for 3 px-groups (96 px = 2 rows x 48)
    int bases[3], opx[3];
#pragma unroll
    for (int g = 0; g < 3; ++g) {
        int px = g * 32 + pxg;               // 0..95
        int rr = (px >= 48) ? 1 : 0;
        int cc = px - rr * 48;
        bases[g] = rr * ROW_STRIDE + cc + 1; // gather col = cc + dj - 1 (+2 shift)
        opx[g]   = (r0 + rr) * NW + cc;
    }

    const float4* mptr  = meta + (size_t)o0 * META_F4;
    float*        pbase = out + ((size_t)b * OUT_CH + o0) * NPIX;

    // prologue: offsets for i=0
    float4 F0 = mptr[0], F1 = mptr[1];

#pragma unroll 1
    for (int i = 0; i < 8; ++i) {
        // prefetch next iteration's offsets (last iter reads 1 pad record; never used)
        float4 N0 = mptr[META_F4 + 0];
        float4 N1 = mptr[META_F4 + 1];

        // weights for current channel (latency overlaps the ds_read phase)
        float4 W0 = mptr[2], W1 = mptr[3], W2 = mptr[4];
        float4 W3 = mptr[5], W4 = mptr[6], W5 = mptr[7], W6 = mptr[8];

        const int off0 = __float_as_int(F0.x);
        const int off1 = __float_as_int(F0.y);
        const int off2 = __float_as_int(F0.z);
        const int off3 = __float_as_int(F0.w);
        const int off4 = __float_as_int(F1.x);
        const int off5 = __float_as_int(F1.y);
        const int off6 = __float_as_int(F1.z);
        const int off7 = __float_as_int(F1.w);

#pragma unroll
        for (int g = 0; g < 3; ++g) {
            const int bg = bases[g];
            float v0 = lds[off0 + bg];
            float v1 = lds[off1 + bg];
            float v2 = lds[off2 + bg];
            float v3 = lds[off3 + bg];
            float v4 = lds[off4 + bg];
            float v5 = lds[off5 + bg];
            float v6 = lds[off6 + bg];
            float v7 = lds[off7 + bg];
            float t0 = fmaf(v1, fmaf(W0.w, v0, W0.z), fmaf(W0.y, v0, W0.x));
            float t1 = fmaf(v3, fmaf(W1.w, v2, W1.z), fmaf(W1.y, v2, W1.x));
            float t2 = fmaf(v5, fmaf(W2.w, v4, W2.z), fmaf(W2.y, v4, W2.x));
            float t3 = fmaf(v7, fmaf(W3.w, v6, W3.z), fmaf(W3.y, v6, W3.x));
            float u0 = fmaf(t1, fmaf(W4.w, t0, W4.z), fmaf(W4.y, t0, W4.x));
            float u1 = fmaf(t3, fmaf(W5.w, t2, W5.z), fmaf(W5.y, t2, W5.x));
            float y  = fmaf(u1, fmaf(W6.w, u0, W6.z), fmaf(W6.y, u0, W6.x));
            pbase[opx[g]] = y;
        }

        F0 = N0; F1 = N1;
        mptr  += META_F4;
        pbase += NPIX;
    }
}

extern "C" void kernel_launch(void* const* d_in, const int* in_sizes, int n_in,
                              void* d_out, int out_size, void* d_ws, size_t ws_size,
                              hipStream_t stream) {
    const float* x        = (const float*)d_in[0];
    const float* logits   = (const float*)d_in[1];
    const int*   leaf_idx = (const int*)d_in[2];
    float*       out      = (float*)d_out;
    float*       meta     = (float*)d_ws;    // 256*36 dwords = 36,864 B (+pad in ws)

    prep_kernel<<<15, 256, 0, stream>>>(logits, leaf_idx, meta);

    dim3 grid(24, 2, NB);
    ltc_kernel<<<grid, 512, 0, stream>>>(x, (const float4*)meta, out);
}